// Round 1
// baseline (634.681 us; speedup 1.0000x reference)
//
#include <hip/hip_runtime.h>
#include <math.h>

// CapsuleLayer fused kernel (fp32, round 1: correctness + baseline)
// Stage 1: u_pre = x @ Wp + bp   (GEMM M=131072 N=128 K=768, LDS-tiled, BM=64)
// Stage 2: squash -> u_hat (registers, 16 thr/row) -> 3 routing iters -> v

#define BATCH   131072
#define DDIM    768
#define NP      8
#define NPD     16
#define NC      5
#define NCD     16
#define BM      64
#define BK      32
#define NKSTEP  (DDIM/BK)      // 24

#define XT_STRIDE 68           // x^T tile stride (pad, 16B-aligned rows)
#define SB_OFF    (BK*XT_STRIDE)   // 2176 floats
#define SB_STRIDE 132          // Wp tile stride (pad, 16B-aligned rows)
// W (routing transform) overwrites the staging region after the GEMM.
// Skew by p*4 floats to spread banks; stays 16B aligned.
#define WLDS(p,c,i) ((((p)*NC+(c))*NPD+(i))*NCD + (p)*4)
#define SMEM_FLOATS 10272

__global__ __launch_bounds__(256, 2)
void caps_fused(const float* __restrict__ x, const float* __restrict__ Wp,
                const float* __restrict__ bp, const float* __restrict__ Wg,
                float* __restrict__ out)
{
    __shared__ float sm[SMEM_FLOATS];
    const int tid  = threadIdx.x;
    const int b0   = blockIdx.x * BM;
    const int tm   = tid >> 4;        // 0..15 : row group (4 rows each)
    const int tn   = tid & 15;        // 0..15 : col group (8 cols each)
    const int xrow = tid >> 2;        // 0..63 : staging row
    const int xsub = tid & 3;         // 0..3  : staging k-chunk

    float acc[4][8];
#pragma unroll
    for (int i = 0; i < 4; ++i)
#pragma unroll
        for (int j = 0; j < 8; ++j) acc[i][j] = 0.f;

    const float* xg = x + (size_t)(b0 + xrow) * DDIM + xsub * 4;

    // Wp staging: flat float4 id f in [0,1024): p = f>>7, rem = f&127
    const int f0 = tid, f1 = tid + 256, f2 = tid + 512, f3 = tid + 768;
    const float* wp0 = Wp + (f0 >> 7) * (DDIM * NPD) + (f0 & 127) * 4;
    const float* wp1 = Wp + (f1 >> 7) * (DDIM * NPD) + (f1 & 127) * 4;
    const float* wp2 = Wp + (f2 >> 7) * (DDIM * NPD) + (f2 & 127) * 4;
    const float* wp3 = Wp + (f3 >> 7) * (DDIM * NPD) + (f3 & 127) * 4;
    const int wb0 = SB_OFF + ((f0 & 127) >> 2) * SB_STRIDE + (f0 >> 7) * NPD + (f0 & 3) * 4;
    const int wb1 = SB_OFF + ((f1 & 127) >> 2) * SB_STRIDE + (f1 >> 7) * NPD + (f1 & 3) * 4;
    const int wb2 = SB_OFF + ((f2 & 127) >> 2) * SB_STRIDE + (f2 >> 7) * NPD + (f2 & 3) * 4;
    const int wb3 = SB_OFF + ((f3 & 127) >> 2) * SB_STRIDE + (f3 >> 7) * NPD + (f3 & 3) * 4;

    for (int ks = 0; ks < NKSTEP; ++ks) {
        const int k0 = ks * BK;
        // issue global loads before the barrier (overlap w/ prev compute)
        float4 xa = *(const float4*)(xg + k0);
        float4 xb = *(const float4*)(xg + k0 + 16);
        float4 w0 = *(const float4*)(wp0 + k0 * NPD);
        float4 w1 = *(const float4*)(wp1 + k0 * NPD);
        float4 w2 = *(const float4*)(wp2 + k0 * NPD);
        float4 w3 = *(const float4*)(wp3 + k0 * NPD);
        __syncthreads();
        // x tile, transposed: xT[k][row]
        sm[(xsub*4+0)*XT_STRIDE + xrow] = xa.x;
        sm[(xsub*4+1)*XT_STRIDE + xrow] = xa.y;
        sm[(xsub*4+2)*XT_STRIDE + xrow] = xa.z;
        sm[(xsub*4+3)*XT_STRIDE + xrow] = xa.w;
        sm[(xsub*4+16)*XT_STRIDE + xrow] = xb.x;
        sm[(xsub*4+17)*XT_STRIDE + xrow] = xb.y;
        sm[(xsub*4+18)*XT_STRIDE + xrow] = xb.z;
        sm[(xsub*4+19)*XT_STRIDE + xrow] = xb.w;
        // Wp tile: B[k][p*16+o]
        *(float4*)&sm[wb0] = w0;
        *(float4*)&sm[wb1] = w1;
        *(float4*)&sm[wb2] = w2;
        *(float4*)&sm[wb3] = w3;
        __syncthreads();
#pragma unroll 8
        for (int kk = 0; kk < BK; ++kk) {
            float4 a4  = *(const float4*)&sm[kk*XT_STRIDE + tm*4];
            float4 bq0 = *(const float4*)&sm[SB_OFF + kk*SB_STRIDE + tn*8];
            float4 bq1 = *(const float4*)&sm[SB_OFF + kk*SB_STRIDE + tn*8 + 4];
            const float av[4] = {a4.x, a4.y, a4.z, a4.w};
            const float bv[8] = {bq0.x, bq0.y, bq0.z, bq0.w, bq1.x, bq1.y, bq1.z, bq1.w};
#pragma unroll
            for (int i = 0; i < 4; ++i)
#pragma unroll
                for (int j = 0; j < 8; ++j)
                    acc[i][j] = fmaf(av[i], bv[j], acc[i][j]);
        }
    }

    // bias for this thread's 8 columns
    float bb[8];
    {
        float4 bq0 = *(const float4*)(bp + tn*8);
        float4 bq1 = *(const float4*)(bp + tn*8 + 4);
        bb[0]=bq0.x; bb[1]=bq0.y; bb[2]=bq0.z; bb[3]=bq0.w;
        bb[4]=bq1.x; bb[5]=bq1.y; bb[6]=bq1.z; bb[7]=bq1.w;
    }

    // load routing transform W into LDS (overwrites staging region)
    __syncthreads();
#pragma unroll
    for (int it = 0; it < 10; ++it) {
        const int f4i  = tid + 256*it;   // 2560 float4s
        const int flat = f4i * 4;
        const int p    = flat / 1280;    // 5*16*16 floats per p
        float4 w = ((const float4*)Wg)[f4i];
        *(float4*)&sm[flat + p*4] = w;
    }
    __syncthreads();

    // ---- phase 2: 16 threads per row; this thread owns (pp, j-half jh) ----
    const int pp = tn >> 1;
    const int jh = tn & 1;
    const int j0 = jh * 8;

#pragma unroll
    for (int i = 0; i < 4; ++i) {
        const int row = tm*4 + i;
        // assemble u_pre[row][pp*16 .. +15] from own cols + partner's via shfl
        float ab[8], ot[8];
#pragma unroll
        for (int jj = 0; jj < 8; ++jj) ab[jj] = acc[i][jj] + bb[jj];
#pragma unroll
        for (int jj = 0; jj < 8; ++jj) ot[jj] = __shfl_xor(ab[jj], 1);
        float u[16];
#pragma unroll
        for (int jj = 0; jj < 8; ++jj) {
            u[jj]     = jh ? ot[jj] : ab[jj];
            u[jj + 8] = jh ? ab[jj] : ot[jj];
        }
        // squash over the 16-dim primary capsule
        float sq = 0.f;
#pragma unroll
        for (int q = 0; q < 16; ++q) sq = fmaf(u[q], u[q], sq);
        const float scl = (sq / (1.f + sq)) * (1.f / (sqrtf(sq) + 1e-8f));
#pragma unroll
        for (int q = 0; q < 16; ++q) u[q] *= scl;

        // u_hat[c][jj] = sum_i u[i] * W[pp,c,i,j0+jj]   (registers only)
        float uh[NC][8];
#pragma unroll
        for (int c = 0; c < NC; ++c) {
#pragma unroll
            for (int jj = 0; jj < 8; ++jj) uh[c][jj] = 0.f;
#pragma unroll
            for (int q = 0; q < 16; ++q) {
                const float* wr = &sm[WLDS(pp, c, q) + j0];
                float4 wq0 = *(const float4*)(wr);
                float4 wq1 = *(const float4*)(wr + 4);
                const float uq = u[q];
                uh[c][0] = fmaf(uq, wq0.x, uh[c][0]);
                uh[c][1] = fmaf(uq, wq0.y, uh[c][1]);
                uh[c][2] = fmaf(uq, wq0.z, uh[c][2]);
                uh[c][3] = fmaf(uq, wq0.w, uh[c][3]);
                uh[c][4] = fmaf(uq, wq1.x, uh[c][4]);
                uh[c][5] = fmaf(uq, wq1.y, uh[c][5]);
                uh[c][6] = fmaf(uq, wq1.z, uh[c][6]);
                uh[c][7] = fmaf(uq, wq1.w, uh[c][7]);
            }
        }

        // dynamic routing, 3 iterations
        float blog[NC] = {0.f, 0.f, 0.f, 0.f, 0.f};
        float s[NC][8];
#pragma unroll
        for (int itr = 0; itr < 3; ++itr) {
            float m = blog[0];
#pragma unroll
            for (int c = 1; c < NC; ++c) m = fmaxf(m, blog[c]);
            float e[NC]; float es = 0.f;
#pragma unroll
            for (int c = 0; c < NC; ++c) { e[c] = __expf(blog[c] - m); es += e[c]; }
            const float inv = 1.f / es;
#pragma unroll
            for (int c = 0; c < NC; ++c) {
                const float cc = e[c] * inv;
#pragma unroll
                for (int jj = 0; jj < 8; ++jj) s[c][jj] = cc * uh[c][jj];
            }
            // reduce partial s over the 8 primary capsules (lane bits 1..3)
#pragma unroll
            for (int c = 0; c < NC; ++c) {
#pragma unroll
                for (int jj = 0; jj < 8; ++jj) {
                    float t = s[c][jj];
                    t += __shfl_xor(t, 2);
                    t += __shfl_xor(t, 4);
                    t += __shfl_xor(t, 8);
                    s[c][jj] = t;
                }
            }
            // squash s -> v (in place); |s|^2 needs the other j-half too
#pragma unroll
            for (int c = 0; c < NC; ++c) {
                float ss = 0.f;
#pragma unroll
                for (int jj = 0; jj < 8; ++jj) ss = fmaf(s[c][jj], s[c][jj], ss);
                ss += __shfl_xor(ss, 1);
                const float vs = (ss / (1.f + ss)) * (1.f / (sqrtf(ss) + 1e-8f));
#pragma unroll
                for (int jj = 0; jj < 8; ++jj) s[c][jj] *= vs;
            }
            if (itr < 2) {
#pragma unroll
                for (int c = 0; c < NC; ++c) {
                    float a = 0.f;
#pragma unroll
                    for (int jj = 0; jj < 8; ++jj) a = fmaf(uh[c][jj], s[c][jj], a);
                    a += __shfl_xor(a, 1);   // full dot over j
                    blog[c] += a;
                }
            }
        }

        // write v: thread with pp==c writes class c's half (compile-time select)
        if (pp < NC) {
            float o[8];
#pragma unroll
            for (int jj = 0; jj < 8; ++jj) o[jj] = s[0][jj];
#pragma unroll
            for (int c = 1; c < NC; ++c) {
                const bool sel = (pp == c);
#pragma unroll
                for (int jj = 0; jj < 8; ++jj) o[jj] = sel ? s[c][jj] : o[jj];
            }
            float* og = out + (size_t)(b0 + row) * (NC*NCD) + pp*NCD + j0;
            *(float4*)(og)     = make_float4(o[0], o[1], o[2], o[3]);
            *(float4*)(og + 4) = make_float4(o[4], o[5], o[6], o[7]);
        }
    }
}

extern "C" void kernel_launch(void* const* d_in, const int* in_sizes, int n_in,
                              void* d_out, int out_size, void* d_ws, size_t ws_size,
                              hipStream_t stream) {
    (void)in_sizes; (void)n_in; (void)d_ws; (void)ws_size; (void)out_size;
    const float* x  = (const float*)d_in[0];
    const float* Wp = (const float*)d_in[1];
    const float* bp = (const float*)d_in[2];
    const float* W  = (const float*)d_in[3];
    float* out = (float*)d_out;
    dim3 grid(BATCH / BM);   // 2048 blocks
    caps_fused<<<grid, 256, 0, stream>>>(x, Wp, bp, W, out);
}

// Round 2
// 261.263 us; speedup vs baseline: 2.4293x; 2.4293x over previous
//
#include <hip/hip_runtime.h>
#include <math.h>

// CapsuleLayer fused, round 2: MFMA GEMM (split-bf16 hi/lo, fp32-accurate)
// + DPP-based routing reductions.
//
// prep kernel : Wp [8,768,16] fp32 -> frag-ready bf16 hi/lo images in d_ws
// main kernel : per block (64 rows):
//   GEMM  u_pre = x @ WpT  via mfma_f32_16x16x32_bf16, 3 products
//         (xh*wh + xl*wh + xh*wl), A-frags direct from global, B double-
//         buffered in LDS (16KB/K-step).
//   4 passes: write acc[*][p] -> uA (8.7KB LDS), 256 thr = 16 rows x 16
//         (p,jh) slots, squash -> votes (W fp32 in LDS) -> 3 routing iters
//         with DPP row_ror (p-sum) / quad_perm (jh-sum) reductions.

#define BATCH 131072
#define DDIM  768
#define NP    8
#define NPD   16
#define NC    5
#define NCD   16
#define BM    64
#define NKS   24        // 768/32

typedef __attribute__((ext_vector_type(8))) short short8;
typedef __attribute__((ext_vector_type(4))) float f32x4;

// W (routing transform) LDS layout, skewed by p*4 floats (round-1 proven)
#define WLDS(p,c,i) ((((p)*NC+(c))*NPD+(i))*NCD + (p)*4)
#define UA_OFF    10272
#define UA_STRIDE 136
#define SMEM_FLOATS (UA_OFF + 16*UA_STRIDE)   // 12448 floats = 49792 B

__device__ __forceinline__ unsigned short f2b_rne(float f) {
    unsigned u = __builtin_bit_cast(unsigned, f);
    u += 0x7fffu + ((u >> 16) & 1u);
    return (unsigned short)(u >> 16);
}
__device__ __forceinline__ float b2f(unsigned short h) {
    unsigned u = ((unsigned)h) << 16;
    return __builtin_bit_cast(float, u);
}
template<int CTRL>
__device__ __forceinline__ float dpp_add(float v) {
    int s = __builtin_amdgcn_update_dpp(0, __builtin_bit_cast(int, v),
                                        CTRL, 0xf, 0xf, false);
    return v + __builtin_bit_cast(float, s);
}
// sum over the 8 same-parity lanes of a 16-lane DPP row (preserves bit0=jh)
__device__ __forceinline__ float rowsum8(float v) {
    v = dpp_add<0x122>(v);   // row_ror:2
    v = dpp_add<0x124>(v);   // row_ror:4
    v = dpp_add<0x128>(v);   // row_ror:8
    return v;
}
// v + v(lane^1): quad_perm(1,0,3,2)
__device__ __forceinline__ float pairsum(float v) { return dpp_add<0xB1>(v); }

// ---- prep: Wp -> frag-ready bf16 hi/lo per-K-step images -----------------
// image per ks (16384 B): hi bytes [0,8192): col*64 + k*2 ; lo at +8192
__global__ void caps_prep(const float* __restrict__ Wp,
                          unsigned short* __restrict__ wpt) {
    const int idx = blockIdx.x * 256 + threadIdx.x;   // < 98304
    const int ks  = idx >> 12;
    const int r   = idx & 4095;
    const int k   = r >> 7;       // 0..31
    const int col = r & 127;      // p*16+o
    const float v = Wp[(col >> 4) * (DDIM * NPD) + (ks * 32 + k) * NPD + (col & 15)];
    const unsigned short hi = f2b_rne(v);
    const unsigned short lo = f2b_rne(v - b2f(hi));
    wpt[ks * 8192 + col * 32 + k]        = hi;
    wpt[ks * 8192 + 4096 + col * 32 + k] = lo;
}

// ---- main ----------------------------------------------------------------
__global__ __launch_bounds__(256, 3)
void caps_main(const float* __restrict__ x, const float* __restrict__ bp,
               const float* __restrict__ Wg, const unsigned short* __restrict__ wpt,
               float* __restrict__ out)
{
    __shared__ float smf[SMEM_FLOATS];
    char* smc = (char*)smf;
    const int tid  = threadIdx.x;
    const int w    = tid >> 6;         // wave 0..3
    const int lane = tid & 63;
    const int ln   = lane & 15;        // A row / B col within tile
    const int g    = lane >> 4;        // k-block 0..3
    const int b0   = blockIdx.x * BM;

    f32x4 acc[8];
#pragma unroll
    for (int t = 0; t < 8; ++t) acc[t] = (f32x4){0.f, 0.f, 0.f, 0.f};

    const float* xrow = x + (size_t)(b0 + w * 16 + ln) * DDIM + g * 8;
    const char*  wptc = (const char*)wpt;

    // prologue: stage ks=0 B image into buf0
    float4 sv[4];
#pragma unroll
    for (int q = 0; q < 4; ++q)
        sv[q] = *(const float4*)(wptc + (q * 256 + tid) * 16);
    float4 xa = *(const float4*)(xrow);
    float4 xb = *(const float4*)(xrow + 4);
#pragma unroll
    for (int q = 0; q < 4; ++q)
        *(float4*)(smc + (q * 256 + tid) * 16) = sv[q];
    __syncthreads();

    for (int ks = 0; ks < NKS; ++ks) {
        const char* cur = smc + (ks & 1) * 16384;
        char*       nxt = smc + ((ks + 1) & 1) * 16384;
        float4 nxa, nxb;
        if (ks < NKS - 1) {
            const char* wim = wptc + (size_t)(ks + 1) * 16384;
#pragma unroll
            for (int q = 0; q < 4; ++q)
                sv[q] = *(const float4*)(wim + (q * 256 + tid) * 16);
            nxa = *(const float4*)(xrow + (ks + 1) * 32);
            nxb = *(const float4*)(xrow + (ks + 1) * 32 + 4);
        }
        // A fragment: fp32 -> bf16 hi/lo
        const float av[8] = {xa.x, xa.y, xa.z, xa.w, xb.x, xb.y, xb.z, xb.w};
        short8 ah, al;
#pragma unroll
        for (int e = 0; e < 8; ++e) {
            const unsigned short h = f2b_rne(av[e]);
            ah[e] = (short)h;
            al[e] = (short)f2b_rne(av[e] - b2f(h));
        }
#pragma unroll
        for (int t = 0; t < 8; ++t) {
            const int fo = (t * 16 + ln) * 64 + g * 16;
            short8 bh = *(const short8*)(cur + fo);
            short8 bl = *(const short8*)(cur + 8192 + fo);
            acc[t] = __builtin_amdgcn_mfma_f32_16x16x32_bf16(ah, bh, acc[t], 0, 0, 0);
            acc[t] = __builtin_amdgcn_mfma_f32_16x16x32_bf16(al, bh, acc[t], 0, 0, 0);
            acc[t] = __builtin_amdgcn_mfma_f32_16x16x32_bf16(ah, bl, acc[t], 0, 0, 0);
        }
        if (ks < NKS - 1) {
#pragma unroll
            for (int q = 0; q < 4; ++q)
                *(float4*)(nxt + (q * 256 + tid) * 16) = sv[q];
            xa = nxa; xb = nxb;
        }
        __syncthreads();
    }

    // load routing transform W (fp32, skewed) into LDS [0, 41088)
    {
        const float4* wg4 = (const float4*)Wg;
#pragma unroll
        for (int q = 0; q < 10; ++q) {
            const int f4i  = q * 256 + tid;      // < 2560
            const int flat = f4i * 4;
            const int p    = flat / 1280;
            float4 wv = wg4[f4i];
            *(float4*)&smf[flat + p * 4] = wv;
        }
    }

    // phase-2 thread roles
    const int tm = tid >> 4, tn = tid & 15;
    const int pp = tn >> 1, jh = tn & 1, j0 = jh * 8;
    float bb[16];
#pragma unroll
    for (int q = 0; q < 4; ++q) {
        float4 b4 = *(const float4*)(bp + pp * NPD + q * 4);
        bb[q * 4 + 0] = b4.x; bb[q * 4 + 1] = b4.y;
        bb[q * 4 + 2] = b4.z; bb[q * 4 + 3] = b4.w;
    }
    float* uA = smf + UA_OFF;

    for (int p = 0; p < 4; ++p) {
        // every wave dumps acc[*][p] (rows == p mod 4 of its 16-row tile)
#pragma unroll
        for (int pc = 0; pc < 4; ++pc) if (pc == p) {
#pragma unroll
            for (int t = 0; t < 8; ++t)
                uA[(w * 4 + g) * UA_STRIDE + t * 16 + ln] = acc[t][pc];
        }
        __syncthreads();

        // ---- one row per thread ----
        float u[16];
#pragma unroll
        for (int q = 0; q < 4; ++q) {
            float4 u4 = *(const float4*)&uA[tm * UA_STRIDE + pp * NPD + q * 4];
            u[q * 4 + 0] = u4.x + bb[q * 4 + 0];
            u[q * 4 + 1] = u4.y + bb[q * 4 + 1];
            u[q * 4 + 2] = u4.z + bb[q * 4 + 2];
            u[q * 4 + 3] = u4.w + bb[q * 4 + 3];
        }
        float sq = 0.f;
#pragma unroll
        for (int q = 0; q < 16; ++q) sq = fmaf(u[q], u[q], sq);
        const float scl = (sq / (1.f + sq)) * (1.f / (sqrtf(sq) + 1e-8f));
#pragma unroll
        for (int q = 0; q < 16; ++q) u[q] *= scl;

        // votes u_hat (registers), W from LDS (4-way broadcast across tm)
        float uh[NC][8];
#pragma unroll
        for (int c = 0; c < NC; ++c) {
#pragma unroll
            for (int jj = 0; jj < 8; ++jj) uh[c][jj] = 0.f;
#pragma unroll
            for (int q = 0; q < 16; ++q) {
                const float* wr = &smf[WLDS(pp, c, q) + j0];
                float4 w0 = *(const float4*)(wr);
                float4 w1 = *(const float4*)(wr + 4);
                const float uq = u[q];
                uh[c][0] = fmaf(uq, w0.x, uh[c][0]);
                uh[c][1] = fmaf(uq, w0.y, uh[c][1]);
                uh[c][2] = fmaf(uq, w0.z, uh[c][2]);
                uh[c][3] = fmaf(uq, w0.w, uh[c][3]);
                uh[c][4] = fmaf(uq, w1.x, uh[c][4]);
                uh[c][5] = fmaf(uq, w1.y, uh[c][5]);
                uh[c][6] = fmaf(uq, w1.z, uh[c][6]);
                uh[c][7] = fmaf(uq, w1.w, uh[c][7]);
            }
        }

        // dynamic routing, 3 iterations (DPP reductions)
        float blog[NC] = {0.f, 0.f, 0.f, 0.f, 0.f};
        float s[NC][8];
#pragma unroll
        for (int itr = 0; itr < 3; ++itr) {
            float m = blog[0];
#pragma unroll
            for (int c = 1; c < NC; ++c) m = fmaxf(m, blog[c]);
            float e[NC]; float es = 0.f;
#pragma unroll
            for (int c = 0; c < NC; ++c) { e[c] = __expf(blog[c] - m); es += e[c]; }
            const float inv = 1.f / es;
#pragma unroll
            for (int c = 0; c < NC; ++c) {
                const float cc = e[c] * inv;
#pragma unroll
                for (int jj = 0; jj < 8; ++jj) s[c][jj] = cc * uh[c][jj];
            }
#pragma unroll
            for (int c = 0; c < NC; ++c)
#pragma unroll
                for (int jj = 0; jj < 8; ++jj) s[c][jj] = rowsum8(s[c][jj]);
#pragma unroll
            for (int c = 0; c < NC; ++c) {
                float ss = 0.f;
#pragma unroll
                for (int jj = 0; jj < 8; ++jj) ss = fmaf(s[c][jj], s[c][jj], ss);
                ss = pairsum(ss);
                const float vs = (ss / (1.f + ss)) * (1.f / (sqrtf(ss) + 1e-8f));
#pragma unroll
                for (int jj = 0; jj < 8; ++jj) s[c][jj] *= vs;
            }
            if (itr < 2) {
#pragma unroll
                for (int c = 0; c < NC; ++c) {
                    float a = 0.f;
#pragma unroll
                    for (int jj = 0; jj < 8; ++jj) a = fmaf(uh[c][jj], s[c][jj], a);
                    a = pairsum(a);
                    blog[c] += a;
                }
            }
        }

        if (pp < NC) {
            float o[8];
#pragma unroll
            for (int jj = 0; jj < 8; ++jj) o[jj] = s[0][jj];
#pragma unroll
            for (int c = 1; c < NC; ++c) {
                const bool sel = (pp == c);
#pragma unroll
                for (int jj = 0; jj < 8; ++jj) o[jj] = sel ? s[c][jj] : o[jj];
            }
            const int row_glob = b0 + (tm >> 2) * 16 + (tm & 3) * 4 + p;
            float* og = out + (size_t)row_glob * (NC * NCD) + pp * NCD + j0;
            *(float4*)(og)     = make_float4(o[0], o[1], o[2], o[3]);
            *(float4*)(og + 4) = make_float4(o[4], o[5], o[6], o[7]);
        }
        if (p < 3) __syncthreads();
    }
}

extern "C" void kernel_launch(void* const* d_in, const int* in_sizes, int n_in,
                              void* d_out, int out_size, void* d_ws, size_t ws_size,
                              hipStream_t stream) {
    (void)in_sizes; (void)n_in; (void)ws_size; (void)out_size;
    const float* x  = (const float*)d_in[0];
    const float* Wp = (const float*)d_in[1];
    const float* bp = (const float*)d_in[2];
    const float* W  = (const float*)d_in[3];
    float* out = (float*)d_out;
    unsigned short* wpt = (unsigned short*)d_ws;   // 393216 B used

    caps_prep<<<384, 256, 0, stream>>>(Wp, wpt);
    caps_main<<<BATCH / BM, 256, 0, stream>>>(x, bp, W, wpt, out);
}